// Round 1
// baseline (15996.637 us; speedup 1.0000x reference)
//
#include <hip/hip_runtime.h>
#include <math.h>

// STCCapsNet forward, fp32 reference-exact pipeline.
// B=32, C=1, H=W=64, HP=WP=28, NUM_PRIM=32, DIM_CAPS=8, IN_CAPS=25088,
// NUM_CLASSES=2, OUT_DIM=16, TEMP_CH=4.
//
// Workspace layout (bytes), peak ~238.9 MB:
//   A   @ 0           : 134,217,728  s3 (B,256,64,64) -> fused (in-place) -> u_hat (102.8MB)
//   B   @ 134,217,728 :  67,108,864  s2 (B,128,64,64); later b_ij (6.4MB @ B+0), p raw (25.7MB @ B+8MB)
//   C   @ 201,326,592 :  33,554,432  s1 (B,64,64,64); later u (25.7MB)
//   tail@ 234,881,024 :  t1, t2, t3, w_fT, sj_part, v

#define BSZ 32

// ---------------------------------------------------------------- conv1d k=5 pad=2 + relu
__global__ __launch_bounds__(256) void conv1d_relu_k(
    const float* __restrict__ in, const float* __restrict__ w,
    const float* __restrict__ bias, float* __restrict__ out, int CI, int CO) {
  int idx = blockIdx.x * 256 + threadIdx.x;
  int total = BSZ * CO * 64;
  if (idx >= total) return;
  int x = idx & 63;
  int co = (idx >> 6) % CO;
  int b = idx / (64 * CO);
  const float* ip = in + (size_t)b * CI * 64;
  const float* wp = w + (size_t)co * CI * 5;
  float acc = bias[co];
  for (int ci = 0; ci < CI; ++ci) {
    const float* ir = ip + ci * 64;
    const float* wr_ = wp + ci * 5;
#pragma unroll
    for (int k = 0; k < 5; ++k) {
      int xx = x + k - 2;
      if (xx >= 0 && xx < 64) acc += ir[xx] * wr_[k];
    }
  }
  out[idx] = fmaxf(acc, 0.f);
}

// ---------------------------------------------------------------- conv2d 3x3 pad=1 + relu
// block 256: thread = (co_l = t&15) x (pixel group g = t>>4 -> 4x4 block of 4x4 px)
// grid: (16 tiles of 16x16, CO/16, B)
template <int CI, int CIC>
__global__ __launch_bounds__(256) void conv3x3_relu_k(
    const float* __restrict__ in, const float* __restrict__ w,
    const float* __restrict__ bias, float* __restrict__ out, int CO) {
  __shared__ float in_t[CIC][18][20];
  __shared__ float w_t[CIC][16][12];
  int t = threadIdx.x;
  int co_l = t & 15;
  int g = t >> 4;
  int gy = g >> 2, gx = g & 3;
  int y0 = (blockIdx.x >> 2) * 16, x0 = (blockIdx.x & 3) * 16;
  int co = blockIdx.y * 16 + co_l;
  int b = blockIdx.z;
  float acc[16];
#pragma unroll
  for (int i = 0; i < 16; ++i) acc[i] = 0.f;

  for (int cib = 0; cib < CI / CIC; ++cib) {
    int ci0 = cib * CIC;
    for (int s = t; s < CIC * 324; s += 256) {
      int ci = s / 324;
      int r = s - ci * 324;
      int iy = r / 18, ix = r - iy * 18;
      int gyy = y0 + iy - 1, gxx = x0 + ix - 1;
      float v = 0.f;
      if (gyy >= 0 && gyy < 64 && gxx >= 0 && gxx < 64)
        v = in[((size_t)b * CI + ci0 + ci) * 4096 + gyy * 64 + gxx];
      in_t[ci][iy][ix] = v;
    }
    for (int s = t; s < CIC * 144; s += 256) {
      int ci = s / 144;
      int r = s - ci * 144;
      int cw = r / 9, k = r - cw * 9;
      w_t[ci][cw][k] = w[((size_t)(blockIdx.y * 16 + cw) * CI + ci0 + ci) * 9 + k];
    }
    __syncthreads();
    for (int ci = 0; ci < CIC; ++ci) {
      float wv[9];
#pragma unroll
      for (int k = 0; k < 9; ++k) wv[k] = w_t[ci][co_l][k];
      float pin[36];
#pragma unroll
      for (int r6 = 0; r6 < 6; ++r6)
#pragma unroll
        for (int c6 = 0; c6 < 6; ++c6)
          pin[r6 * 6 + c6] = in_t[ci][4 * gy + r6][4 * gx + c6];
#pragma unroll
      for (int py = 0; py < 4; ++py)
#pragma unroll
        for (int px = 0; px < 4; ++px) {
          float s_ = acc[py * 4 + px];
#pragma unroll
          for (int ky = 0; ky < 3; ++ky)
#pragma unroll
            for (int kx = 0; kx < 3; ++kx)
              s_ += pin[(py + ky) * 6 + (px + kx)] * wv[ky * 3 + kx];
          acc[py * 4 + px] = s_;
        }
    }
    __syncthreads();
  }
  float bv = bias[co];
#pragma unroll
  for (int py = 0; py < 4; ++py)
#pragma unroll
    for (int px = 0; px < 4; ++px)
      out[((size_t)b * CO + co) * 4096 + (size_t)(y0 + 4 * gy + py) * 64 +
          (x0 + 4 * gx + px)] = fmaxf(acc[py * 4 + px] + bv, 0.f);
}

// ---------------------------------------------------------------- w_f transpose (256,260)->(260,256)
__global__ __launch_bounds__(256) void transpose_wf_k(const float* __restrict__ wf,
                                                      float* __restrict__ wfT) {
  int idx = blockIdx.x * 256 + threadIdx.x;
  if (idx >= 256 * 260) return;
  int co = idx / 260, c = idx - co * 260;
  wfT[c * 256 + co] = wf[idx];
}

// ---------------------------------------------------------------- 1x1 fusion conv, IN-PLACE on s3 buffer
// a holds s3 (B,256,4096); logical input channels 0..3 from t3 view, 4..259 from a.
// block = 256 co, 32 pixels; stage all 260 ch for the pixels in LDS, sync, overwrite.
__global__ __launch_bounds__(256) void fuse1x1_k(const float* __restrict__ t3,
                                                 const float* __restrict__ wfT,
                                                 const float* __restrict__ bf,
                                                 float* __restrict__ a) {
  __shared__ float in_t[260][32];
  int t = threadIdx.x;
  int b = blockIdx.x >> 7;
  int p0 = (blockIdx.x & 127) * 32;
  for (int s = t; s < 260 * 32; s += 256) {
    int c = s >> 5, pp = s & 31;
    float v;
    if (c < 4)
      v = t3[(size_t)b * 16384 + c * 4096 + p0 + pp];
    else
      v = a[((size_t)b * 256 + (c - 4)) * 4096 + p0 + pp];
    in_t[c][pp] = v;
  }
  __syncthreads();
  int co = t;
  float acc[32];
#pragma unroll
  for (int pp = 0; pp < 32; ++pp) acc[pp] = 0.f;
  for (int c = 0; c < 260; ++c) {
    float wv = wfT[c * 256 + co];
#pragma unroll
    for (int pp = 0; pp < 32; ++pp) acc[pp] += wv * in_t[c][pp];
  }
  float bv = bf[co];
#pragma unroll
  for (int pp = 0; pp < 32; ++pp)
    a[((size_t)b * 256 + co) * 4096 + p0 + pp] = acc[pp] + bv;
}

// ---------------------------------------------------------------- 9x9 stride-2 valid conv (primary caps)
// out p (B,256,28,28). block 256: thread = co-pair (c2=t&7 -> co 2*c2,2*c2+1) x
// pixel slot (ps=t>>3: sy=ps>>2 rows {2sy,2sy+1}, sx=ps&3 cols {4sx..4sx+3}) -> 16 acc.
// grid: (4 tiles of 16x16 out px (padded past 28), 16 co chunks, B)
__global__ __launch_bounds__(256) void conv9x9s2_k(const float* __restrict__ in,
                                                   const float* __restrict__ w,
                                                   const float* __restrict__ bias,
                                                   float* __restrict__ p) {
  const int CIC = 4;
  __shared__ float in_t[CIC][39][40];
  __shared__ float w_t[16][CIC * 81 + 1];
  int t = threadIdx.x;
  int c2 = t & 7;
  int ps = t >> 3;
  int sy = ps >> 2, sx = ps & 3;
  int y0 = (blockIdx.x >> 1) * 16, x0 = (blockIdx.x & 1) * 16;
  int co0 = blockIdx.y * 16;
  int b = blockIdx.z;
  float acc[16];
#pragma unroll
  for (int i = 0; i < 16; ++i) acc[i] = 0.f;

  for (int cib = 0; cib < 256 / CIC; ++cib) {
    int ci0 = cib * CIC;
    for (int s = t; s < CIC * 1521; s += 256) {
      int ci = s / 1521;
      int r = s - ci * 1521;
      int iy = r / 39, ix = r - iy * 39;
      int gy = 2 * y0 + iy, gx = 2 * x0 + ix;
      float v = 0.f;
      if (gy < 64 && gx < 64)
        v = in[((size_t)b * 256 + ci0 + ci) * 4096 + gy * 64 + gx];
      in_t[ci][iy][ix] = v;
    }
    for (int s = t; s < 16 * CIC * 81; s += 256) {
      int cw = s / 324;
      int r = s - cw * 324;  // r = ci*81 + k
      w_t[cw][r] = w[((size_t)(co0 + cw) * 256 + ci0) * 81 + r];
    }
    __syncthreads();
    for (int ci = 0; ci < CIC; ++ci) {
      for (int ky = 0; ky < 9; ++ky) {
        float rowA[15], rowB[15];
#pragma unroll
        for (int cc = 0; cc < 15; ++cc) {
          rowA[cc] = in_t[ci][4 * sy + ky][8 * sx + cc];
          rowB[cc] = in_t[ci][4 * sy + 2 + ky][8 * sx + cc];
        }
#pragma unroll
        for (int kx = 0; kx < 9; ++kx) {
          float w0 = w_t[2 * c2 + 0][ci * 81 + ky * 9 + kx];
          float w1 = w_t[2 * c2 + 1][ci * 81 + ky * 9 + kx];
#pragma unroll
          for (int j = 0; j < 4; ++j) {
            float va = rowA[2 * j + kx], vb = rowB[2 * j + kx];
            acc[0 + 0 + j] += w0 * va;
            acc[0 + 4 + j] += w0 * vb;
            acc[8 + 0 + j] += w1 * va;
            acc[8 + 4 + j] += w1 * vb;
          }
        }
      }
    }
    __syncthreads();
  }
  float bv0 = bias[co0 + 2 * c2], bv1 = bias[co0 + 2 * c2 + 1];
#pragma unroll
  for (int e = 0; e < 2; ++e)
#pragma unroll
    for (int py = 0; py < 2; ++py)
#pragma unroll
      for (int j = 0; j < 4; ++j) {
        int oy = y0 + 2 * sy + py, ox = x0 + 4 * sx + j;
        if (oy < 28 && ox < 28) {
          int co = co0 + 2 * c2 + e;
          p[((size_t)b * 256 + co) * 784 + oy * 28 + ox] =
              acc[e * 8 + py * 4 + j] + (e ? bv1 : bv0);
        }
      }
}

// ---------------------------------------------------------------- capsule squash: p(B,256,784) -> u(B,25088,8)
__global__ __launch_bounds__(256) void squash_caps_k(const float* __restrict__ p,
                                                     float* __restrict__ u) {
  int idx = blockIdx.x * 256 + threadIdx.x;
  if (idx >= BSZ * 25088) return;
  int b = idx / 25088;
  int cap = idx - b * 25088;
  int prim = cap / 784, pix = cap - prim * 784;
  const float* pp = p + ((size_t)b * 256 + prim * 8) * 784 + pix;
  float x[8];
  float sn = 0.f;
#pragma unroll
  for (int d = 0; d < 8; ++d) {
    x[d] = pp[(size_t)d * 784];
    sn += x[d] * x[d];
  }
  float scale = sn / ((1.f + sn) * sqrtf(sn + 1e-8f));
  float4 r0 = {x[0] * scale, x[1] * scale, x[2] * scale, x[3] * scale};
  float4 r1 = {x[4] * scale, x[5] * scale, x[6] * scale, x[7] * scale};
  float4* dst = (float4*)(u + (size_t)idx * 8);
  dst[0] = r0;
  dst[1] = r1;
}

// ---------------------------------------------------------------- u_hat = einsum('iodk,bik->biod')
__global__ __launch_bounds__(256) void uhat_k(const float* __restrict__ u,
                                              const float* __restrict__ w_r,
                                              float* __restrict__ u_hat) {
  int i = blockIdx.x * 256 + threadIdx.x;  // 25088
  int b = blockIdx.y;
  const float4* up = (const float4*)(u + ((size_t)b * 25088 + i) * 8);
  float4 ua = up[0], ub = up[1];
  const float4* wr = (const float4*)(w_r + (size_t)i * 256);
  float res[32];
#pragma unroll
  for (int od = 0; od < 32; ++od) {
    float4 wa = wr[od * 2], wb = wr[od * 2 + 1];
    res[od] = wa.x * ua.x + wa.y * ua.y + wa.z * ua.z + wa.w * ua.w +
              wb.x * ub.x + wb.y * ub.y + wb.z * ub.z + wb.w * ub.w;
  }
  float4* dst = (float4*)(u_hat + ((size_t)b * 25088 + i) * 32);
#pragma unroll
  for (int q = 0; q < 8; ++q)
    dst[q] = make_float4(res[4 * q], res[4 * q + 1], res[4 * q + 2], res[4 * q + 3]);
}

// ---------------------------------------------------------------- routing: partial s_j per (b,seg)
__global__ __launch_bounds__(256) void route_sj_k(const float* __restrict__ u_hat,
                                                  const float* __restrict__ b_ij,
                                                  float* __restrict__ sj_part, int iter) {
  int b = blockIdx.x;
  int seg = blockIdx.y;
  int t = threadIdx.x;
  float acc[32];
#pragma unroll
  for (int j = 0; j < 32; ++j) acc[j] = 0.f;
  int i0 = seg * 3136;
  for (int i = i0 + t; i < i0 + 3136; i += 256) {
    float c0 = 0.5f, c1 = 0.5f;
    if (iter > 0) {
      float b0 = b_ij[((size_t)b * 25088 + i) * 2 + 0];
      float b1 = b_ij[((size_t)b * 25088 + i) * 2 + 1];
      float m = fmaxf(b0, b1);
      float e0 = expf(b0 - m), e1 = expf(b1 - m);
      float inv = 1.f / (e0 + e1);
      c0 = e0 * inv;
      c1 = e1 * inv;
    }
    const float4* uh = (const float4*)(u_hat + ((size_t)b * 25088 + i) * 32);
#pragma unroll
    for (int q = 0; q < 4; ++q) {
      float4 va = uh[q];
      acc[4 * q + 0] += c0 * va.x;
      acc[4 * q + 1] += c0 * va.y;
      acc[4 * q + 2] += c0 * va.z;
      acc[4 * q + 3] += c0 * va.w;
      float4 vb = uh[4 + q];
      acc[16 + 4 * q + 0] += c1 * vb.x;
      acc[16 + 4 * q + 1] += c1 * vb.y;
      acc[16 + 4 * q + 2] += c1 * vb.z;
      acc[16 + 4 * q + 3] += c1 * vb.w;
    }
  }
#pragma unroll
  for (int j = 0; j < 32; ++j) {
    acc[j] += __shfl_down(acc[j], 32);
    acc[j] += __shfl_down(acc[j], 16);
    acc[j] += __shfl_down(acc[j], 8);
    acc[j] += __shfl_down(acc[j], 4);
    acc[j] += __shfl_down(acc[j], 2);
    acc[j] += __shfl_down(acc[j], 1);
  }
  __shared__ float red[4][32];
  int wave = t >> 6, lane = t & 63;
  if (lane == 0) {
#pragma unroll
    for (int j = 0; j < 32; ++j) red[wave][j] = acc[j];
  }
  __syncthreads();
  if (t < 32) {
    float s = red[0][t] + red[1][t] + red[2][t] + red[3][t];
    sj_part[((size_t)b * 8 + seg) * 32 + t] = s;
  }
}

// ---------------------------------------------------------------- routing: finalize v = squash_elem(sum segs)
__global__ __launch_bounds__(256) void route_fin_k(const float* __restrict__ sj_part,
                                                   float* __restrict__ v,
                                                   float* __restrict__ out, int final_it) {
  int idx = blockIdx.x * 256 + threadIdx.x;
  if (idx >= BSZ * 32) return;
  int b = idx >> 5, j = idx & 31;
  float s = 0.f;
#pragma unroll
  for (int seg = 0; seg < 8; ++seg) s += sj_part[((size_t)b * 8 + seg) * 32 + j];
  float sn = s * s;
  float vv = sn * s / ((1.f + sn) * sqrtf(sn + 1e-8f));
  v[idx] = vv;
  if (final_it) out[idx] = fabsf(vv);
}

// ---------------------------------------------------------------- routing: b_ij update
__global__ __launch_bounds__(256) void route_upd_k(const float* __restrict__ u_hat,
                                                   const float* __restrict__ v,
                                                   float* __restrict__ b_ij, int first) {
  int i = blockIdx.x * 256 + threadIdx.x;  // 25088
  int b = blockIdx.y;
  const float4* uh = (const float4*)(u_hat + ((size_t)b * 25088 + i) * 32);
  const float4* vp = (const float4*)(v + b * 32);
  float e0 = 0.f, e1 = 0.f;
#pragma unroll
  for (int q = 0; q < 4; ++q) {
    float4 a = uh[q], wv = vp[q];
    e0 += a.x * wv.x + a.y * wv.y + a.z * wv.z + a.w * wv.w;
    float4 a2 = uh[4 + q], w2 = vp[4 + q];
    e1 += a2.x * w2.x + a2.y * w2.y + a2.z * w2.z + a2.w * w2.w;
  }
  size_t o = ((size_t)b * 25088 + i) * 2;
  if (first) {
    b_ij[o + 0] = e0;
    b_ij[o + 1] = e1;
  } else {
    b_ij[o + 0] += e0;
    b_ij[o + 1] += e1;
  }
}

// ================================================================ launch
extern "C" void kernel_launch(void* const* d_in, const int* in_sizes, int n_in,
                              void* d_out, int out_size, void* d_ws, size_t ws_size,
                              hipStream_t stream) {
  (void)in_sizes; (void)n_in; (void)out_size;
  const float* x    = (const float*)d_in[0];
  const float* w_t1 = (const float*)d_in[1];
  const float* b_t1 = (const float*)d_in[2];
  const float* w_t2 = (const float*)d_in[3];
  const float* b_t2 = (const float*)d_in[4];
  const float* w_t3 = (const float*)d_in[5];
  const float* b_t3 = (const float*)d_in[6];
  const float* w_s1 = (const float*)d_in[7];
  const float* b_s1 = (const float*)d_in[8];
  const float* w_s2 = (const float*)d_in[9];
  const float* b_s2 = (const float*)d_in[10];
  const float* w_s3 = (const float*)d_in[11];
  const float* b_s3 = (const float*)d_in[12];
  const float* w_f  = (const float*)d_in[13];
  const float* b_f  = (const float*)d_in[14];
  const float* w_p  = (const float*)d_in[15];
  const float* b_p  = (const float*)d_in[16];
  const float* w_r  = (const float*)d_in[17];
  float* out = (float*)d_out;

  char* ws = (char*)d_ws;
  // requires ws_size >= ~238.9 MB; if smaller we bail (output stays poisoned -> visible failure)
  if (ws_size < 238854144ull) return;
  float* A    = (float*)(ws + 0);                       // s3 / fused / u_hat
  float* s2   = (float*)(ws + 134217728);               // s2
  float* b_ij = (float*)(ws + 134217728);               // b_ij (after s2 dead)
  float* praw = (float*)(ws + 134217728 + 8388608);     // raw primary conv out
  float* s1   = (float*)(ws + 201326592);               // s1
  float* u    = (float*)(ws + 201326592);               // u (after s1 dead)
  float* t1   = (float*)(ws + 234881024);
  float* t2   = (float*)(ws + 235405312);
  float* t3   = (float*)(ws + 236453888);
  float* wfT  = (float*)(ws + 238551040);
  float* sjp  = (float*)(ws + 238817280);
  float* vbuf = (float*)(ws + 238850048);

  // temporal branch (x viewed as (B,64,64))
  conv1d_relu_k<<<512, 256, 0, stream>>>(x, w_t1, b_t1, t1, 64, 64);
  conv1d_relu_k<<<1024, 256, 0, stream>>>(t1, w_t2, b_t2, t2, 64, 128);
  conv1d_relu_k<<<2048, 256, 0, stream>>>(t2, w_t3, b_t3, t3, 128, 256);

  // spectral branch
  conv3x3_relu_k<1, 1><<<dim3(16, 4, BSZ), 256, 0, stream>>>(x, w_s1, b_s1, s1, 64);
  conv3x3_relu_k<64, 8><<<dim3(16, 8, BSZ), 256, 0, stream>>>(s1, w_s2, b_s2, s2, 128);
  conv3x3_relu_k<128, 8><<<dim3(16, 16, BSZ), 256, 0, stream>>>(s2, w_s3, b_s3, A, 256);

  // fusion (in-place on A)
  transpose_wf_k<<<261, 256, 0, stream>>>(w_f, wfT);
  fuse1x1_k<<<4096, 256, 0, stream>>>(t3, wfT, b_f, A);

  // primary capsules
  conv9x9s2_k<<<dim3(4, 16, BSZ), 256, 0, stream>>>(A, w_p, b_p, praw);
  squash_caps_k<<<3136, 256, 0, stream>>>(praw, u);

  // u_hat (overwrites A; fused no longer needed)
  uhat_k<<<dim3(98, BSZ), 256, 0, stream>>>(u, w_r, A);

  // dynamic routing, 3 iterations
  route_sj_k<<<dim3(BSZ, 8), 256, 0, stream>>>(A, b_ij, sjp, 0);
  route_fin_k<<<4, 256, 0, stream>>>(sjp, vbuf, out, 0);
  route_upd_k<<<dim3(98, BSZ), 256, 0, stream>>>(A, vbuf, b_ij, 1);

  route_sj_k<<<dim3(BSZ, 8), 256, 0, stream>>>(A, b_ij, sjp, 1);
  route_fin_k<<<4, 256, 0, stream>>>(sjp, vbuf, out, 0);
  route_upd_k<<<dim3(98, BSZ), 256, 0, stream>>>(A, vbuf, b_ij, 0);

  route_sj_k<<<dim3(BSZ, 8), 256, 0, stream>>>(A, b_ij, sjp, 2);
  route_fin_k<<<4, 256, 0, stream>>>(sjp, vbuf, out, 1);
}

// Round 3
// 4748.113 us; speedup vs baseline: 3.3691x; 3.3691x over previous
//
#include <hip/hip_runtime.h>
#include <math.h>

// STCCapsNet forward. B=32, C=1, H=W=64, HP=WP=28, IN_CAPS=25088, OUT 32x2x16.
// Round 3: 9x9/s2 conv via bf16 MFMA with hi/lo split (3 passes: Ah*Bh + Al*Bh + Ah*Bl)
// for ~fp32 accuracy. Fusion is fp32 in-place (round-1 style); A-planes converted
// fp32->bf16(hi|lo) on the fly during LDS staging.
//
// Workspace (bytes), fits in 238,854,144:
//   fused fp32 @ 0           : 134,217,728  (s3 in-place; dead after conv9x9) -> uhat @0 after
//   praw       @ 134,217,728 :  25,690,112  (over s2-dead)
//   u          @ 159,907,840 :  25,690,112
//   s1         @ 201,326,592 :  33,554,432  (dead after s2 conv)
//   wT_hi      @ 201,326,592 :  10,616,832  (over s1)
//   wT_lo      @ 211,943,424 :  10,616,832
//   b_ij       @ 222,560,256 :   6,422,528
//   tail       @ 234,881,024 :  t1,t2,t3,wfT,sjp,vbuf

#define BSZ 32

typedef unsigned short u16;
using bf16x8 = __attribute__((ext_vector_type(8))) short;
using f32x4 = __attribute__((ext_vector_type(4))) float;

__device__ inline u16 f2bf(float f) {
  union { float f; unsigned u; } v; v.f = f;
  unsigned r = v.u + 0x7FFF + ((v.u >> 16) & 1);
  return (u16)(r >> 16);
}
__device__ inline float bf2f(u16 h) {
  union { unsigned u; float f; } v; v.u = ((unsigned)h) << 16;
  return v.f;
}

// ---------------------------------------------------------------- conv1d k=5 pad=2 + relu
__global__ __launch_bounds__(256) void conv1d_relu_k(
    const float* __restrict__ in, const float* __restrict__ w,
    const float* __restrict__ bias, float* __restrict__ out, int CI, int CO) {
  int idx = blockIdx.x * 256 + threadIdx.x;
  int total = BSZ * CO * 64;
  if (idx >= total) return;
  int x = idx & 63;
  int co = (idx >> 6) % CO;
  int b = idx / (64 * CO);
  const float* ip = in + (size_t)b * CI * 64;
  const float* wp = w + (size_t)co * CI * 5;
  float acc = bias[co];
  for (int ci = 0; ci < CI; ++ci) {
    const float* ir = ip + ci * 64;
    const float* wr_ = wp + ci * 5;
#pragma unroll
    for (int k = 0; k < 5; ++k) {
      int xx = x + k - 2;
      if (xx >= 0 && xx < 64) acc += ir[xx] * wr_[k];
    }
  }
  out[idx] = fmaxf(acc, 0.f);
}

// ---------------------------------------------------------------- conv2d 3x3 pad=1 + relu
template <int CI, int CIC>
__global__ __launch_bounds__(256) void conv3x3_relu_k(
    const float* __restrict__ in, const float* __restrict__ w,
    const float* __restrict__ bias, float* __restrict__ out, int CO) {
  __shared__ float in_t[CIC][18][20];
  __shared__ float w_t[CIC][16][12];
  int t = threadIdx.x;
  int co_l = t & 15;
  int g = t >> 4;
  int gy = g >> 2, gx = g & 3;
  int y0 = (blockIdx.x >> 2) * 16, x0 = (blockIdx.x & 3) * 16;
  int co = blockIdx.y * 16 + co_l;
  int b = blockIdx.z;
  float acc[16];
#pragma unroll
  for (int i = 0; i < 16; ++i) acc[i] = 0.f;

  for (int cib = 0; cib < CI / CIC; ++cib) {
    int ci0 = cib * CIC;
    for (int s = t; s < CIC * 324; s += 256) {
      int ci = s / 324;
      int r = s - ci * 324;
      int iy = r / 18, ix = r - iy * 18;
      int gyy = y0 + iy - 1, gxx = x0 + ix - 1;
      float v = 0.f;
      if (gyy >= 0 && gyy < 64 && gxx >= 0 && gxx < 64)
        v = in[((size_t)b * CI + ci0 + ci) * 4096 + gyy * 64 + gxx];
      in_t[ci][iy][ix] = v;
    }
    for (int s = t; s < CIC * 144; s += 256) {
      int ci = s / 144;
      int r = s - ci * 144;
      int cw = r / 9, k = r - cw * 9;
      w_t[ci][cw][k] = w[((size_t)(blockIdx.y * 16 + cw) * CI + ci0 + ci) * 9 + k];
    }
    __syncthreads();
    for (int ci = 0; ci < CIC; ++ci) {
      float wv[9];
#pragma unroll
      for (int k = 0; k < 9; ++k) wv[k] = w_t[ci][co_l][k];
      float pin[36];
#pragma unroll
      for (int r6 = 0; r6 < 6; ++r6)
#pragma unroll
        for (int c6 = 0; c6 < 6; ++c6)
          pin[r6 * 6 + c6] = in_t[ci][4 * gy + r6][4 * gx + c6];
#pragma unroll
      for (int py = 0; py < 4; ++py)
#pragma unroll
        for (int px = 0; px < 4; ++px) {
          float s_ = acc[py * 4 + px];
#pragma unroll
          for (int ky = 0; ky < 3; ++ky)
#pragma unroll
            for (int kx = 0; kx < 3; ++kx)
              s_ += pin[(py + ky) * 6 + (px + kx)] * wv[ky * 3 + kx];
          acc[py * 4 + px] = s_;
        }
    }
    __syncthreads();
  }
  float bv = bias[co];
#pragma unroll
  for (int py = 0; py < 4; ++py)
#pragma unroll
    for (int px = 0; px < 4; ++px)
      out[((size_t)b * CO + co) * 4096 + (size_t)(y0 + 4 * gy + py) * 64 +
          (x0 + 4 * gx + px)] = fmaxf(acc[py * 4 + px] + bv, 0.f);
}

// ---------------------------------------------------------------- w_f transpose (256,260)->(260,256)
__global__ __launch_bounds__(256) void transpose_wf_k(const float* __restrict__ wf,
                                                      float* __restrict__ wfT) {
  int idx = blockIdx.x * 256 + threadIdx.x;
  if (idx >= 256 * 260) return;
  int co = idx / 260, c = idx - co * 260;
  wfT[c * 256 + co] = wf[idx];
}

// ---------------------------------------------------------------- w_p -> WT_hi/WT_lo [g*81+tap][co][ci%32]
__global__ __launch_bounds__(256) void transpose_wp_k(const float* __restrict__ wp,
                                                      u16* __restrict__ wth,
                                                      u16* __restrict__ wtl) {
  int s = blockIdx.x;  // 0..647 = g*81 + tap
  int g = s / 81, t = s - g * 81;
  int co = threadIdx.x;
  u16 th[32], tl[32];
#pragma unroll
  for (int c = 0; c < 32; ++c) {
    float f = wp[((size_t)co * 256 + g * 32 + c) * 81 + t];
    u16 h = f2bf(f);
    th[c] = h;
    tl[c] = f2bf(f - bf2f(h));
  }
  ushort4* dh = (ushort4*)(wth + ((size_t)s * 256 + co) * 32);
  ushort4* dl = (ushort4*)(wtl + ((size_t)s * 256 + co) * 32);
#pragma unroll
  for (int q = 0; q < 8; ++q) {
    dh[q] = make_ushort4(th[4 * q], th[4 * q + 1], th[4 * q + 2], th[4 * q + 3]);
    dl[q] = make_ushort4(tl[4 * q], tl[4 * q + 1], tl[4 * q + 2], tl[4 * q + 3]);
  }
}

// ---------------------------------------------------------------- 1x1 fusion conv, fp32 IN-PLACE on s3
__global__ __launch_bounds__(256) void fuse1x1_k(const float* __restrict__ t3,
                                                 const float* __restrict__ wfT,
                                                 const float* __restrict__ bf,
                                                 float* __restrict__ a) {
  __shared__ float in_t[260][32];
  int t = threadIdx.x;
  int b = blockIdx.x >> 7;
  int p0 = (blockIdx.x & 127) * 32;
  for (int s = t; s < 260 * 32; s += 256) {
    int c = s >> 5, pp = s & 31;
    float v;
    if (c < 4)
      v = t3[(size_t)b * 16384 + c * 4096 + p0 + pp];
    else
      v = a[((size_t)b * 256 + (c - 4)) * 4096 + p0 + pp];
    in_t[c][pp] = v;
  }
  __syncthreads();
  int co = t;
  float acc[32];
#pragma unroll
  for (int pp = 0; pp < 32; ++pp) acc[pp] = 0.f;
  for (int c = 0; c < 260; ++c) {
    float wv = wfT[c * 256 + co];
#pragma unroll
    for (int pp = 0; pp < 32; ++pp) acc[pp] += wv * in_t[c][pp];
  }
  float bv = bf[co];
#pragma unroll
  for (int pp = 0; pp < 32; ++pp)
    a[((size_t)b * 256 + co) * 4096 + p0 + pp] = acc[pp] + bv;
}

// ---------------------------------------------------------------- 9x9 s2 conv, MFMA, hi/lo 3-pass
// grid (7 tiles of 128 px, 32 batch), 512 thr = 8 waves (2M x 4N). Per wave 4x4 16x16 tiles.
// Pass 0: Ah*Bh, pass 1: Al*Bh, pass 2: Ah*Bl; fp32 accumulate across all passes.
__global__ __launch_bounds__(512) void conv9x9_mfma_k(const float* __restrict__ fused,
                                                      const u16* __restrict__ WTh,
                                                      const u16* __restrict__ WTl,
                                                      const float* __restrict__ bias,
                                                      float* __restrict__ praw) {
  __shared__ __align__(16) char lds_a[19 * 63 * 80];   // 95760 B: [row][x][32ci bf16], 80B stride
  __shared__ __align__(16) char lds_b[2][256 * 80];    // 2 x 20480 B: [co][32ci bf16], 80B stride
  const int tid = threadIdx.x;
  const int b = blockIdx.y, tile = blockIdx.x;
  const int p0 = tile * 128;
  const int oy0 = p0 / 28;
  const int w = tid >> 6, l = tid & 63;
  const int wm = w >> 2, wn = w & 3;
  const int kb = l >> 4, il = l & 15;

  int abase[4];
#pragma unroll
  for (int mb = 0; mb < 4; ++mb) {
    int p = p0 + (wm * 4 + mb) * 16 + il;
    int oy = p / 28, ox = p - oy * 28;
    abase[mb] = ((2 * (oy - oy0)) * 63 + 2 * ox) * 80 + kb * 16;
  }
  int bbase[4];
#pragma unroll
  for (int nbi = 0; nbi < 4; ++nbi)
    bbase[nbi] = (wn * 64 + nbi * 16 + il) * 80 + kb * 16;

  f32x4 acc[4][4];
#pragma unroll
  for (int mb = 0; mb < 4; ++mb)
#pragma unroll
    for (int nbi = 0; nbi < 4; ++nbi) {
      f32x4 z = {0.f, 0.f, 0.f, 0.f};
      acc[mb][nbi] = z;
    }

  const float* Fb = fused + (size_t)b * 256 * 4096;
  float4 nb0, nb1;

  // stage A plane (hi: plane=0, lo: plane=1) for channel group g
  auto stageA = [&](int g, int plane) {
    const float* src = Fb + (size_t)g * 32 * 4096;
    for (int s = tid; s < 19 * 63 * 8; s += 512) {
      int ciq = s / (19 * 63);
      int rem = s - ciq * (19 * 63);
      int r = rem / 63, x2 = rem - r * 63;
      int iy = 2 * oy0 + r;
      float a0 = 0.f, a1 = 0.f, a2 = 0.f, a3 = 0.f;
      if (iy < 64) {
        const float* pp0 = src + (size_t)(ciq * 4) * 4096 + iy * 64 + x2;
        a0 = pp0[0];
        a1 = pp0[4096];
        a2 = pp0[8192];
        a3 = pp0[12288];
      }
      u16 e0, e1, e2, e3;
      if (plane == 0) {
        e0 = f2bf(a0); e1 = f2bf(a1); e2 = f2bf(a2); e3 = f2bf(a3);
      } else {
        u16 h0 = f2bf(a0), h1 = f2bf(a1), h2 = f2bf(a2), h3 = f2bf(a3);
        e0 = f2bf(a0 - bf2f(h0)); e1 = f2bf(a1 - bf2f(h1));
        e2 = f2bf(a2 - bf2f(h2)); e3 = f2bf(a3 - bf2f(h3));
      }
      *(ushort4*)(lds_a + (size_t)(r * 63 + x2) * 80 + ciq * 8) =
          make_ushort4(e0, e1, e2, e3);
    }
  };
  auto prefB = [&](int stepn) {
    int sb = stepn % 648;
    const u16* W = (stepn >= 1296) ? WTl : WTh;
    const char* p = (const char*)W + (size_t)sb * 16384;
    nb0 = *(const float4*)(p + tid * 16);
    nb1 = *(const float4*)(p + (tid + 512) * 16);
  };
  auto writeB = [&](int buf) {
    int u0 = tid, u1 = tid + 512;
    *(float4*)(&lds_b[buf][(u0 >> 2) * 80 + (u0 & 3) * 16]) = nb0;
    *(float4*)(&lds_b[buf][(u1 >> 2) * 80 + (u1 & 3) * 16]) = nb1;
  };

  stageA(0, 0);
  prefB(0);
  writeB(0);

  int step = 0;
  for (int pass = 0; pass < 3; ++pass) {
    for (int g = 0; g < 8; ++g) {
      for (int t = 0; t < 81; ++t, ++step) {
        __syncthreads();
        if (step < 1943) prefB(step + 1);
        int ky = t / 9, kx = t - ky * 9;
        int koff = (ky * 63 + kx) * 80;
        int bsel = step & 1;
        bf16x8 av[4], bv[4];
#pragma unroll
        for (int mb = 0; mb < 4; ++mb)
          av[mb] = *(const bf16x8*)(lds_a + abase[mb] + koff);
#pragma unroll
        for (int nbi = 0; nbi < 4; ++nbi)
          bv[nbi] = *(const bf16x8*)(&lds_b[bsel][bbase[nbi]]);
#pragma unroll
        for (int mb = 0; mb < 4; ++mb)
#pragma unroll
          for (int nbi = 0; nbi < 4; ++nbi)
            acc[mb][nbi] = __builtin_amdgcn_mfma_f32_16x16x32_bf16(
                av[mb], bv[nbi], acc[mb][nbi], 0, 0, 0);
        if (step < 1943) writeB((step + 1) & 1);
        if (t == 80 && step < 1943) {
          __syncthreads();
          int ns = step + 1;
          int npass = ns / 648;
          int ng = (ns % 648) / 81;
          stageA(ng, (npass == 1) ? 1 : 0);
        }
      }
    }
  }

  // epilogue: D row = pixel = Mbase + kb*4 + reg, col = co = Nbase + il
#pragma unroll
  for (int mb = 0; mb < 4; ++mb) {
    int pixb = p0 + (wm * 4 + mb) * 16 + kb * 4;
    if (pixb < 784) {
#pragma unroll
      for (int nbi = 0; nbi < 4; ++nbi) {
        int co = wn * 64 + nbi * 16 + il;
        float bv_ = bias[co];
        f32x4 a = acc[mb][nbi];
        float4 o = make_float4(a[0] + bv_, a[1] + bv_, a[2] + bv_, a[3] + bv_);
        *(float4*)(praw + (size_t)(b * 256 + co) * 784 + pixb) = o;
      }
    }
  }
}

// ---------------------------------------------------------------- capsule squash: p(B,256,784) -> u(B,25088,8)
__global__ __launch_bounds__(256) void squash_caps_k(const float* __restrict__ p,
                                                     float* __restrict__ u) {
  int idx = blockIdx.x * 256 + threadIdx.x;
  if (idx >= BSZ * 25088) return;
  int b = idx / 25088;
  int cap = idx - b * 25088;
  int prim = cap / 784, pix = cap - prim * 784;
  const float* pp = p + ((size_t)b * 256 + prim * 8) * 784 + pix;
  float x[8];
  float sn = 0.f;
#pragma unroll
  for (int d = 0; d < 8; ++d) {
    x[d] = pp[(size_t)d * 784];
    sn += x[d] * x[d];
  }
  float scale = sn / ((1.f + sn) * sqrtf(sn + 1e-8f));
  float4 r0 = {x[0] * scale, x[1] * scale, x[2] * scale, x[3] * scale};
  float4 r1 = {x[4] * scale, x[5] * scale, x[6] * scale, x[7] * scale};
  float4* dst = (float4*)(u + (size_t)idx * 8);
  dst[0] = r0;
  dst[1] = r1;
}

// ---------------------------------------------------------------- u_hat = einsum('iodk,bik->biod')
__global__ __launch_bounds__(256) void uhat_k(const float* __restrict__ u,
                                              const float* __restrict__ w_r,
                                              float* __restrict__ u_hat) {
  int i = blockIdx.x * 256 + threadIdx.x;  // 25088
  int b = blockIdx.y;
  const float4* up = (const float4*)(u + ((size_t)b * 25088 + i) * 8);
  float4 ua = up[0], ub = up[1];
  const float4* wr = (const float4*)(w_r + (size_t)i * 256);
  float res[32];
#pragma unroll
  for (int od = 0; od < 32; ++od) {
    float4 wa = wr[od * 2], wb = wr[od * 2 + 1];
    res[od] = wa.x * ua.x + wa.y * ua.y + wa.z * ua.z + wa.w * ua.w +
              wb.x * ub.x + wb.y * ub.y + wb.z * ub.z + wb.w * ub.w;
  }
  float4* dst = (float4*)(u_hat + ((size_t)b * 25088 + i) * 32);
#pragma unroll
  for (int q = 0; q < 8; ++q)
    dst[q] = make_float4(res[4 * q], res[4 * q + 1], res[4 * q + 2], res[4 * q + 3]);
}

// ---------------------------------------------------------------- routing: partial s_j per (b,seg)
__global__ __launch_bounds__(256) void route_sj_k(const float* __restrict__ u_hat,
                                                  const float* __restrict__ b_ij,
                                                  float* __restrict__ sj_part, int iter) {
  int b = blockIdx.x;
  int seg = blockIdx.y;
  int t = threadIdx.x;
  float acc[32];
#pragma unroll
  for (int j = 0; j < 32; ++j) acc[j] = 0.f;
  int i0 = seg * 3136;
  for (int i = i0 + t; i < i0 + 3136; i += 256) {
    float c0 = 0.5f, c1 = 0.5f;
    if (iter > 0) {
      float b0 = b_ij[((size_t)b * 25088 + i) * 2 + 0];
      float b1 = b_ij[((size_t)b * 25088 + i) * 2 + 1];
      float m = fmaxf(b0, b1);
      float e0 = expf(b0 - m), e1 = expf(b1 - m);
      float inv = 1.f / (e0 + e1);
      c0 = e0 * inv;
      c1 = e1 * inv;
    }
    const float4* uh = (const float4*)(u_hat + ((size_t)b * 25088 + i) * 32);
#pragma unroll
    for (int q = 0; q < 4; ++q) {
      float4 va = uh[q];
      acc[4 * q + 0] += c0 * va.x;
      acc[4 * q + 1] += c0 * va.y;
      acc[4 * q + 2] += c0 * va.z;
      acc[4 * q + 3] += c0 * va.w;
      float4 vb = uh[4 + q];
      acc[16 + 4 * q + 0] += c1 * vb.x;
      acc[16 + 4 * q + 1] += c1 * vb.y;
      acc[16 + 4 * q + 2] += c1 * vb.z;
      acc[16 + 4 * q + 3] += c1 * vb.w;
    }
  }
#pragma unroll
  for (int j = 0; j < 32; ++j) {
    acc[j] += __shfl_down(acc[j], 32);
    acc[j] += __shfl_down(acc[j], 16);
    acc[j] += __shfl_down(acc[j], 8);
    acc[j] += __shfl_down(acc[j], 4);
    acc[j] += __shfl_down(acc[j], 2);
    acc[j] += __shfl_down(acc[j], 1);
  }
  __shared__ float red[4][32];
  int wave = t >> 6, lane = t & 63;
  if (lane == 0) {
#pragma unroll
    for (int j = 0; j < 32; ++j) red[wave][j] = acc[j];
  }
  __syncthreads();
  if (t < 32) {
    float s = red[0][t] + red[1][t] + red[2][t] + red[3][t];
    sj_part[((size_t)b * 8 + seg) * 32 + t] = s;
  }
}

// ---------------------------------------------------------------- routing: finalize v
__global__ __launch_bounds__(256) void route_fin_k(const float* __restrict__ sj_part,
                                                   float* __restrict__ v,
                                                   float* __restrict__ out, int final_it) {
  int idx = blockIdx.x * 256 + threadIdx.x;
  if (idx >= BSZ * 32) return;
  int b = idx >> 5, j = idx & 31;
  float s = 0.f;
#pragma unroll
  for (int seg = 0; seg < 8; ++seg) s += sj_part[((size_t)b * 8 + seg) * 32 + j];
  float sn = s * s;
  float vv = sn * s / ((1.f + sn) * sqrtf(sn + 1e-8f));
  v[idx] = vv;
  if (final_it) out[idx] = fabsf(vv);
}

// ---------------------------------------------------------------- routing: b_ij update
__global__ __launch_bounds__(256) void route_upd_k(const float* __restrict__ u_hat,
                                                   const float* __restrict__ v,
                                                   float* __restrict__ b_ij, int first) {
  int i = blockIdx.x * 256 + threadIdx.x;  // 25088
  int b = blockIdx.y;
  const float4* uh = (const float4*)(u_hat + ((size_t)b * 25088 + i) * 32);
  const float4* vp = (const float4*)(v + b * 32);
  float e0 = 0.f, e1 = 0.f;
#pragma unroll
  for (int q = 0; q < 4; ++q) {
    float4 a = uh[q], wv = vp[q];
    e0 += a.x * wv.x + a.y * wv.y + a.z * wv.z + a.w * wv.w;
    float4 a2 = uh[4 + q], w2 = vp[4 + q];
    e1 += a2.x * w2.x + a2.y * w2.y + a2.z * w2.z + a2.w * w2.w;
  }
  size_t o = ((size_t)b * 25088 + i) * 2;
  if (first) {
    b_ij[o + 0] = e0;
    b_ij[o + 1] = e1;
  } else {
    b_ij[o + 0] += e0;
    b_ij[o + 1] += e1;
  }
}

// ================================================================ launch
extern "C" void kernel_launch(void* const* d_in, const int* in_sizes, int n_in,
                              void* d_out, int out_size, void* d_ws, size_t ws_size,
                              hipStream_t stream) {
  (void)in_sizes; (void)n_in; (void)out_size;
  const float* x    = (const float*)d_in[0];
  const float* w_t1 = (const float*)d_in[1];
  const float* b_t1 = (const float*)d_in[2];
  const float* w_t2 = (const float*)d_in[3];
  const float* b_t2 = (const float*)d_in[4];
  const float* w_t3 = (const float*)d_in[5];
  const float* b_t3 = (const float*)d_in[6];
  const float* w_s1 = (const float*)d_in[7];
  const float* b_s1 = (const float*)d_in[8];
  const float* w_s2 = (const float*)d_in[9];
  const float* b_s2 = (const float*)d_in[10];
  const float* w_s3 = (const float*)d_in[11];
  const float* b_s3 = (const float*)d_in[12];
  const float* w_f  = (const float*)d_in[13];
  const float* b_f  = (const float*)d_in[14];
  const float* w_p  = (const float*)d_in[15];
  const float* b_p  = (const float*)d_in[16];
  const float* w_r  = (const float*)d_in[17];
  float* out = (float*)d_out;

  char* ws = (char*)d_ws;
  if (ws_size < 238854144ull) return;
  float* fused = (float*)(ws + 0);              // s3 -> fused (in-place)
  float* uhat  = (float*)(ws + 0);              // after conv9x9 (fused dead)
  float* praw  = (float*)(ws + 134217728);
  float* u     = (float*)(ws + 159907840);
  float* s2    = (float*)(ws + 134217728);
  float* s1    = (float*)(ws + 201326592);
  u16*   wTh   = (u16*)  (ws + 201326592);
  u16*   wTl   = (u16*)  (ws + 211943424);
  float* b_ij  = (float*)(ws + 222560256);
  float* t1    = (float*)(ws + 234881024);
  float* t2    = (float*)(ws + 235405312);
  float* t3    = (float*)(ws + 236453888);
  float* wfT   = (float*)(ws + 238551040);
  float* sjp   = (float*)(ws + 238817280);
  float* vbuf  = (float*)(ws + 238850048);

  // temporal branch
  conv1d_relu_k<<<512, 256, 0, stream>>>(x, w_t1, b_t1, t1, 64, 64);
  conv1d_relu_k<<<1024, 256, 0, stream>>>(t1, w_t2, b_t2, t2, 64, 128);
  conv1d_relu_k<<<2048, 256, 0, stream>>>(t2, w_t3, b_t3, t3, 128, 256);

  // spectral branch
  conv3x3_relu_k<1, 1><<<dim3(16, 4, BSZ), 256, 0, stream>>>(x, w_s1, b_s1, s1, 64);
  conv3x3_relu_k<64, 8><<<dim3(16, 8, BSZ), 256, 0, stream>>>(s1, w_s2, b_s2, s2, 128);
  conv3x3_relu_k<128, 8><<<dim3(16, 16, BSZ), 256, 0, stream>>>(s2, w_s3, b_s3, fused, 256);

  // weight prep (wTh/wTl overwrite s1 -- dead after s2 conv)
  transpose_wf_k<<<261, 256, 0, stream>>>(w_f, wfT);
  transpose_wp_k<<<648, 256, 0, stream>>>(w_p, wTh, wTl);

  // fusion fp32 in-place
  fuse1x1_k<<<4096, 256, 0, stream>>>(t3, wfT, b_f, fused);

  // primary capsules via MFMA hi/lo
  conv9x9_mfma_k<<<dim3(7, BSZ), 512, 0, stream>>>(fused, wTh, wTl, b_p, praw);
  squash_caps_k<<<3136, 256, 0, stream>>>(praw, u);

  // u_hat (overwrites fused region)
  uhat_k<<<dim3(98, BSZ), 256, 0, stream>>>(u, w_r, uhat);

  // dynamic routing, 3 iterations
  route_sj_k<<<dim3(BSZ, 8), 256, 0, stream>>>(uhat, b_ij, sjp, 0);
  route_fin_k<<<4, 256, 0, stream>>>(sjp, vbuf, out, 0);
  route_upd_k<<<dim3(98, BSZ), 256, 0, stream>>>(uhat, vbuf, b_ij, 1);

  route_sj_k<<<dim3(BSZ, 8), 256, 0, stream>>>(uhat, b_ij, sjp, 1);
  route_fin_k<<<4, 256, 0, stream>>>(sjp, vbuf, out, 0);
  route_upd_k<<<dim3(98, BSZ), 256, 0, stream>>>(uhat, vbuf, b_ij, 0);

  route_sj_k<<<dim3(BSZ, 8), 256, 0, stream>>>(uhat, b_ij, sjp, 2);
  route_fin_k<<<4, 256, 0, stream>>>(sjp, vbuf, out, 1);
}

// Round 5
// 2450.268 us; speedup vs baseline: 6.5285x; 1.9378x over previous
//
#include <hip/hip_runtime.h>
#include <math.h>

// STCCapsNet forward. B=32, C=1, H=W=64, HP=WP=28, IN_CAPS=25088, OUT 32x2x16.
// Round 5: fix round-4 workspace clobber (w3 tables were inside s1's live range).
// conv3x3 MFMA now uses 80B-padded LDS strides (conflict-free, same as conv9x9).
//
// Workspace (bytes), ws >= 238,854,144:
//   fused @ 0           134,217,728  (s3 out, fuse in-place; dead after conv9x9) -> uhat @0
//   s2q   @ 134,217,728  67,108,864  (dead after s3 conv) -> praw @134,217,728 (25.7M),
//                                       u @159,907,840 (25.7M), b_ij @185,597,952 (6.4M)
//   s1    @ 201,326,592  33,554,432  (dead after s2 conv) -> t1 @201,326,592, t2 @201,850,880,
//                                       t3 @202,899,456, wTh @204,996,608, wTl @215,613,440
//   tail  @ 234,881,024: w3a_h/l, w3b_h/l, wfT, sjp, vbuf  (ends 236,658,688)
//
// Order: w3/wf tables -> s1conv -> s2conv(MFMA) -> [temporal conv1d x3, wp tables] ->
//        s3conv(MFMA) -> fuse -> conv9x9(MFMA) -> squash -> uhat -> routing.

#define BSZ 32

typedef unsigned short u16;
using bf16x8 = __attribute__((ext_vector_type(8))) short;
using f32x4 = __attribute__((ext_vector_type(4))) float;

__device__ inline u16 f2bf(float f) {
  union { float f; unsigned u; } v; v.f = f;
  unsigned r = v.u + 0x7FFF + ((v.u >> 16) & 1);
  return (u16)(r >> 16);
}
__device__ inline float bf2f(u16 h) {
  union { unsigned u; float f; } v; v.u = ((unsigned)h) << 16;
  return v.f;
}

// ---------------------------------------------------------------- conv1d k=5 pad=2 + relu
__global__ __launch_bounds__(256) void conv1d_relu_k(
    const float* __restrict__ in, const float* __restrict__ w,
    const float* __restrict__ bias, float* __restrict__ out, int CI, int CO) {
  int idx = blockIdx.x * 256 + threadIdx.x;
  int total = BSZ * CO * 64;
  if (idx >= total) return;
  int x = idx & 63;
  int co = (idx >> 6) % CO;
  int b = idx / (64 * CO);
  const float* ip = in + (size_t)b * CI * 64;
  const float* wp = w + (size_t)co * CI * 5;
  float acc = bias[co];
  for (int ci = 0; ci < CI; ++ci) {
    const float* ir = ip + ci * 64;
    const float* wr_ = wp + ci * 5;
#pragma unroll
    for (int k = 0; k < 5; ++k) {
      int xx = x + k - 2;
      if (xx >= 0 && xx < 64) acc += ir[xx] * wr_[k];
    }
  }
  out[idx] = fmaxf(acc, 0.f);
}

// ---------------------------------------------------------------- conv2d 3x3 pad=1 + relu (scalar; s1 only)
template <int CI, int CIC>
__global__ __launch_bounds__(256) void conv3x3_relu_k(
    const float* __restrict__ in, const float* __restrict__ w,
    const float* __restrict__ bias, float* __restrict__ out, int CO) {
  __shared__ float in_t[CIC][18][20];
  __shared__ float w_t[CIC][16][12];
  int t = threadIdx.x;
  int co_l = t & 15;
  int g = t >> 4;
  int gy = g >> 2, gx = g & 3;
  int y0 = (blockIdx.x >> 2) * 16, x0 = (blockIdx.x & 3) * 16;
  int co = blockIdx.y * 16 + co_l;
  int b = blockIdx.z;
  float acc[16];
#pragma unroll
  for (int i = 0; i < 16; ++i) acc[i] = 0.f;

  for (int cib = 0; cib < CI / CIC; ++cib) {
    int ci0 = cib * CIC;
    for (int s = t; s < CIC * 324; s += 256) {
      int ci = s / 324;
      int r = s - ci * 324;
      int iy = r / 18, ix = r - iy * 18;
      int gyy = y0 + iy - 1, gxx = x0 + ix - 1;
      float v = 0.f;
      if (gyy >= 0 && gyy < 64 && gxx >= 0 && gxx < 64)
        v = in[((size_t)b * CI + ci0 + ci) * 4096 + gyy * 64 + gxx];
      in_t[ci][iy][ix] = v;
    }
    for (int s = t; s < CIC * 144; s += 256) {
      int ci = s / 144;
      int r = s - ci * 144;
      int cw = r / 9, k = r - cw * 9;
      w_t[ci][cw][k] = w[((size_t)(blockIdx.y * 16 + cw) * CI + ci0 + ci) * 9 + k];
    }
    __syncthreads();
    for (int ci = 0; ci < CIC; ++ci) {
      float wv[9];
#pragma unroll
      for (int k = 0; k < 9; ++k) wv[k] = w_t[ci][co_l][k];
      float pin[36];
#pragma unroll
      for (int r6 = 0; r6 < 6; ++r6)
#pragma unroll
        for (int c6 = 0; c6 < 6; ++c6)
          pin[r6 * 6 + c6] = in_t[ci][4 * gy + r6][4 * gx + c6];
#pragma unroll
      for (int py = 0; py < 4; ++py)
#pragma unroll
        for (int px = 0; px < 4; ++px) {
          float s_ = acc[py * 4 + px];
#pragma unroll
          for (int ky = 0; ky < 3; ++ky)
#pragma unroll
            for (int kx = 0; kx < 3; ++kx)
              s_ += pin[(py + ky) * 6 + (px + kx)] * wv[ky * 3 + kx];
          acc[py * 4 + px] = s_;
        }
    }
    __syncthreads();
  }
  float bv = bias[co];
#pragma unroll
  for (int py = 0; py < 4; ++py)
#pragma unroll
    for (int px = 0; px < 4; ++px)
      out[((size_t)b * CO + co) * 4096 + (size_t)(y0 + 4 * gy + py) * 64 +
          (x0 + 4 * gx + px)] = fmaxf(acc[py * 4 + px] + bv, 0.f);
}

// ---------------------------------------------------------------- w_f transpose (256,260)->(260,256)
__global__ __launch_bounds__(256) void transpose_wf_k(const float* __restrict__ wf,
                                                      float* __restrict__ wfT) {
  int idx = blockIdx.x * 256 + threadIdx.x;
  if (idx >= 256 * 260) return;
  int co = idx / 260, c = idx - co * 260;
  wfT[c * 256 + co] = wf[idx];
}

// ---------------------------------------------------------------- w_p -> WT_hi/WT_lo [g*81+tap][co][ci%32]
__global__ __launch_bounds__(256) void transpose_wp_k(const float* __restrict__ wp,
                                                      u16* __restrict__ wth,
                                                      u16* __restrict__ wtl) {
  int s = blockIdx.x;  // 0..647 = g*81 + tap
  int g = s / 81, t = s - g * 81;
  int co = threadIdx.x;
  u16 th[32], tl[32];
#pragma unroll
  for (int c = 0; c < 32; ++c) {
    float f = wp[((size_t)co * 256 + g * 32 + c) * 81 + t];
    u16 h = f2bf(f);
    th[c] = h;
    tl[c] = f2bf(f - bf2f(h));
  }
  ushort4* dh = (ushort4*)(wth + ((size_t)s * 256 + co) * 32);
  ushort4* dl = (ushort4*)(wtl + ((size_t)s * 256 + co) * 32);
#pragma unroll
  for (int q = 0; q < 8; ++q) {
    dh[q] = make_ushort4(th[4 * q], th[4 * q + 1], th[4 * q + 2], th[4 * q + 3]);
    dl[q] = make_ushort4(tl[4 * q], tl[4 * q + 1], tl[4 * q + 2], tl[4 * q + 3]);
  }
}

// ---------------------------------------------------------------- w3 (CO,CI,3,3) -> [g*9+tap][co][32] hi/lo
template <int CO, int NCHUNK>
__global__ __launch_bounds__(256) void transpose_w3_k(const float* __restrict__ w,
                                                      u16* __restrict__ wh,
                                                      u16* __restrict__ wl) {
  int tab = blockIdx.x;  // NCHUNK*9
  int g = tab / 9, tap = tab - g * 9;
  int co = threadIdx.x;
  if (co >= CO) return;
  constexpr int CI = NCHUNK * 32;
  u16 th[32], tl[32];
#pragma unroll
  for (int c = 0; c < 32; ++c) {
    float f = w[((size_t)co * CI + g * 32 + c) * 9 + tap];
    u16 h = f2bf(f);
    th[c] = h;
    tl[c] = f2bf(f - bf2f(h));
  }
  ushort4* dh = (ushort4*)(wh + ((size_t)tab * CO + co) * 32);
  ushort4* dl = (ushort4*)(wl + ((size_t)tab * CO + co) * 32);
#pragma unroll
  for (int q = 0; q < 8; ++q) {
    dh[q] = make_ushort4(th[4 * q], th[4 * q + 1], th[4 * q + 2], th[4 * q + 3]);
    dl[q] = make_ushort4(tl[4 * q], tl[4 * q + 1], tl[4 * q + 2], tl[4 * q + 3]);
  }
}

// ---------------------------------------------------------------- conv3x3 pad=1 s=1 via MFMA hi/lo 3-pass + relu
// 512 thr = 8 waves (WMxWN); wave = 4mb x 4nbi 16x16 tiles; M-tile = WM image rows (WM*64 px).
// LDS strides 80B (conflict-free fragment reads, same as conv9x9).
template <int WM, int WN, int NCHUNK, int CO>
__global__ __launch_bounds__(512) void conv3x3_mfma_k(const float* __restrict__ in,
                                                      const u16* __restrict__ Wh,
                                                      const u16* __restrict__ Wl,
                                                      const float* __restrict__ bias,
                                                      float* __restrict__ out) {
  constexpr int CI = NCHUNK * 32;
  constexpr int ROWS = WM + 2;
  constexpr int KSTEPS = NCHUNK * 9;
  constexpr int NSTEPS = 3 * KSTEPS;
  constexpr int NV4 = CO / 128;
  __shared__ __align__(16) char lds_a[ROWS * 66 * 80];
  __shared__ __align__(16) char lds_b[2][CO * 80];
  const int tid = threadIdx.x;
  const int b = blockIdx.y;
  const int y0 = blockIdx.x * WM;
  const int w = tid >> 6, l = tid & 63;
  const int wm = w / WN, wn = w % WN;
  const int kb = l >> 4, il = l & 15;

  int abase[4];
#pragma unroll
  for (int mb = 0; mb < 4; ++mb) {
    int lp = (wm * 4 + mb) * 16 + il;
    int ly = lp >> 6, lx = lp & 63;
    abase[mb] = (ly * 66 + lx) * 80 + kb * 16;
  }
  int bbase[4];
#pragma unroll
  for (int nbi = 0; nbi < 4; ++nbi)
    bbase[nbi] = (wn * 64 + nbi * 16 + il) * 80 + kb * 16;

  f32x4 acc[4][4];
#pragma unroll
  for (int mb = 0; mb < 4; ++mb)
#pragma unroll
    for (int nbi = 0; nbi < 4; ++nbi) {
      f32x4 z = {0.f, 0.f, 0.f, 0.f};
      acc[mb][nbi] = z;
    }

  const float* Fb = in + (size_t)b * CI * 4096;
  float4 nb[NV4];

  auto stageA = [&](int g, int plane) {
    const float* src = Fb + (size_t)g * 32 * 4096;
    for (int s = tid; s < ROWS * 66 * 8; s += 512) {
      int ciq = s & 7;
      int rest = s >> 3;
      int r = rest / 66, x = rest - r * 66;
      int row = y0 - 1 + r, col = x - 1;
      float a0 = 0.f, a1 = 0.f, a2 = 0.f, a3 = 0.f;
      if (row >= 0 && row < 64 && col >= 0 && col < 64) {
        const float* p = src + (size_t)(ciq * 4) * 4096 + row * 64 + col;
        a0 = p[0];
        a1 = p[4096];
        a2 = p[8192];
        a3 = p[12288];
      }
      u16 e0, e1, e2, e3;
      if (plane == 0) {
        e0 = f2bf(a0); e1 = f2bf(a1); e2 = f2bf(a2); e3 = f2bf(a3);
      } else {
        u16 h0 = f2bf(a0), h1 = f2bf(a1), h2 = f2bf(a2), h3 = f2bf(a3);
        e0 = f2bf(a0 - bf2f(h0)); e1 = f2bf(a1 - bf2f(h1));
        e2 = f2bf(a2 - bf2f(h2)); e3 = f2bf(a3 - bf2f(h3));
      }
      *(ushort4*)(lds_a + (r * 66 + x) * 80 + ciq * 8) = make_ushort4(e0, e1, e2, e3);
    }
  };
  auto prefB = [&](int stepn) {
    int within = stepn % KSTEPS;
    const u16* W = (stepn >= 2 * KSTEPS) ? Wl : Wh;
    const char* p = (const char*)W + (size_t)within * CO * 64;
#pragma unroll
    for (int q = 0; q < NV4; ++q) nb[q] = *(const float4*)(p + (tid + q * 512) * 16);
  };
  auto writeB = [&](int buf) {
#pragma unroll
    for (int q = 0; q < NV4; ++q) {
      int u = tid + q * 512;
      *(float4*)(&lds_b[buf][(u >> 2) * 80 + (u & 3) * 16]) = nb[q];
    }
  };

  stageA(0, 0);
  prefB(0);
  writeB(0);

  int step = 0;
  for (int pass = 0; pass < 3; ++pass) {
    for (int g = 0; g < NCHUNK; ++g) {
      for (int tap = 0; tap < 9; ++tap, ++step) {
        __syncthreads();
        if (step + 1 < NSTEPS) prefB(step + 1);
        int ky = tap / 3, kx = tap - ky * 3;
        int koff = (ky * 66 + kx) * 80;
        int bsel = step & 1;
        bf16x8 av[4], bv[4];
#pragma unroll
        for (int mb = 0; mb < 4; ++mb)
          av[mb] = *(const bf16x8*)(lds_a + abase[mb] + koff);
#pragma unroll
        for (int nbi = 0; nbi < 4; ++nbi)
          bv[nbi] = *(const bf16x8*)(&lds_b[bsel][bbase[nbi]]);
#pragma unroll
        for (int mb = 0; mb < 4; ++mb)
#pragma unroll
          for (int nbi = 0; nbi < 4; ++nbi)
            acc[mb][nbi] = __builtin_amdgcn_mfma_f32_16x16x32_bf16(
                av[mb], bv[nbi], acc[mb][nbi], 0, 0, 0);
        if (step + 1 < NSTEPS) writeB((step + 1) & 1);
        if (tap == 8 && step + 1 < NSTEPS) {
          __syncthreads();
          int ns = step + 1;
          int npass = ns / KSTEPS;
          int ng = (ns % KSTEPS) / 9;
          stageA(ng, (npass == 1) ? 1 : 0);
        }
      }
    }
  }

  const int p0 = y0 * 64;
#pragma unroll
  for (int mb = 0; mb < 4; ++mb) {
    int pixb = p0 + (wm * 4 + mb) * 16 + kb * 4;
#pragma unroll
    for (int nbi = 0; nbi < 4; ++nbi) {
      int co = wn * 64 + nbi * 16 + il;
      float bv_ = bias[co];
      f32x4 a = acc[mb][nbi];
      float4 o = make_float4(fmaxf(a[0] + bv_, 0.f), fmaxf(a[1] + bv_, 0.f),
                             fmaxf(a[2] + bv_, 0.f), fmaxf(a[3] + bv_, 0.f));
      *(float4*)(out + (size_t)(b * CO + co) * 4096 + pixb) = o;
    }
  }
}

// ---------------------------------------------------------------- 1x1 fusion conv, fp32 IN-PLACE
__global__ __launch_bounds__(256) void fuse1x1_k(const float* __restrict__ t3,
                                                 const float* __restrict__ wfT,
                                                 const float* __restrict__ bf,
                                                 float* __restrict__ a) {
  __shared__ float in_t[260][32];
  int t = threadIdx.x;
  int b = blockIdx.x >> 7;
  int p0 = (blockIdx.x & 127) * 32;
  for (int s = t; s < 260 * 32; s += 256) {
    int c = s >> 5, pp = s & 31;
    float v;
    if (c < 4)
      v = t3[(size_t)b * 16384 + c * 4096 + p0 + pp];
    else
      v = a[((size_t)b * 256 + (c - 4)) * 4096 + p0 + pp];
    in_t[c][pp] = v;
  }
  __syncthreads();
  int co = t;
  float acc[32];
#pragma unroll
  for (int pp = 0; pp < 32; ++pp) acc[pp] = 0.f;
  for (int c = 0; c < 260; ++c) {
    float wv = wfT[c * 256 + co];
#pragma unroll
    for (int pp = 0; pp < 32; ++pp) acc[pp] += wv * in_t[c][pp];
  }
  float bv = bf[co];
#pragma unroll
  for (int pp = 0; pp < 32; ++pp)
    a[((size_t)b * 256 + co) * 4096 + p0 + pp] = acc[pp] + bv;
}

// ---------------------------------------------------------------- 9x9 s2 conv, MFMA, hi/lo 3-pass
__global__ __launch_bounds__(512) void conv9x9_mfma_k(const float* __restrict__ fused,
                                                      const u16* __restrict__ WTh,
                                                      const u16* __restrict__ WTl,
                                                      const float* __restrict__ bias,
                                                      float* __restrict__ praw) {
  __shared__ __align__(16) char lds_a[19 * 63 * 80];
  __shared__ __align__(16) char lds_b[2][256 * 80];
  const int tid = threadIdx.x;
  const int b = blockIdx.y, tile = blockIdx.x;
  const int p0 = tile * 128;
  const int oy0 = p0 / 28;
  const int w = tid >> 6, l = tid & 63;
  const int wm = w >> 2, wn = w & 3;
  const int kb = l >> 4, il = l & 15;

  int abase[4];
#pragma unroll
  for (int mb = 0; mb < 4; ++mb) {
    int p = p0 + (wm * 4 + mb) * 16 + il;
    int oy = p / 28, ox = p - oy * 28;
    abase[mb] = ((2 * (oy - oy0)) * 63 + 2 * ox) * 80 + kb * 16;
  }
  int bbase[4];
#pragma unroll
  for (int nbi = 0; nbi < 4; ++nbi)
    bbase[nbi] = (wn * 64 + nbi * 16 + il) * 80 + kb * 16;

  f32x4 acc[4][4];
#pragma unroll
  for (int mb = 0; mb < 4; ++mb)
#pragma unroll
    for (int nbi = 0; nbi < 4; ++nbi) {
      f32x4 z = {0.f, 0.f, 0.f, 0.f};
      acc[mb][nbi] = z;
    }

  const float* Fb = fused + (size_t)b * 256 * 4096;
  float4 nb0, nb1;

  auto stageA = [&](int g, int plane) {
    const float* src = Fb + (size_t)g * 32 * 4096;
    for (int s = tid; s < 19 * 63 * 8; s += 512) {
      int ciq = s / (19 * 63);
      int rem = s - ciq * (19 * 63);
      int r = rem / 63, x2 = rem - r * 63;
      int iy = 2 * oy0 + r;
      float a0 = 0.f, a1 = 0.f, a2 = 0.f, a3 = 0.f;
      if (iy < 64) {
        const float* pp0 = src + (size_t)(ciq * 4) * 4096 + iy * 64 + x2;
        a0 = pp0[0];
        a1 = pp0[4096];
        a2 = pp0[8192];
        a3 = pp0[12288];
      }
      u16 e0, e1, e2, e3;
      if (plane == 0) {
        e0 = f2bf(a0); e1 = f2bf(a1); e2 = f2bf(a2); e3 = f2bf(a3);
      } else {
        u16 h0 = f2bf(a0), h1 = f2bf(a1), h2 = f2bf(a2), h3 = f2bf(a3);
        e0 = f2bf(a0 - bf2f(h0)); e1 = f2bf(a1 - bf2f(h1));
        e2 = f2bf(a2 - bf2f(h2)); e3 = f2bf(a3 - bf2f(h3));
      }
      *(ushort4*)(lds_a + (size_t)(r * 63 + x2) * 80 + ciq * 8) =
          make_ushort4(e0, e1, e2, e3);
    }
  };
  auto prefB = [&](int stepn) {
    int sb = stepn % 648;
    const u16* W = (stepn >= 1296) ? WTl : WTh;
    const char* p = (const char*)W + (size_t)sb * 16384;
    nb0 = *(const float4*)(p + tid * 16);
    nb1 = *(const float4*)(p + (tid + 512) * 16);
  };
  auto writeB = [&](int buf) {
    int u0 = tid, u1 = tid + 512;
    *(float4*)(&lds_b[buf][(u0 >> 2) * 80 + (u0 & 3) * 16]) = nb0;
    *(float4*)(&lds_b[buf][(u1 >> 2) * 80 + (u1 & 3) * 16]) = nb1;
  };

  stageA(0, 0);
  prefB(0);
  writeB(0);

  int step = 0;
  for (int pass = 0; pass < 3; ++pass) {
    for (int g = 0; g < 8; ++g) {
      for (int t = 0; t < 81; ++t, ++step) {
        __syncthreads();
        if (step < 1943) prefB(step + 1);
        int ky = t / 9, kx = t - ky * 9;
        int koff = (ky * 63 + kx) * 80;
        int bsel = step & 1;
        bf16x8 av[4], bv[4];
#pragma unroll
        for (int mb = 0; mb < 4; ++mb)
          av[mb] = *(const bf16x8*)(lds_a + abase[mb] + koff);
#pragma unroll
        for (int nbi = 0; nbi < 4; ++nbi)
          bv[nbi] = *(const bf16x8*)(&lds_b[bsel][bbase[nbi]]);
#pragma unroll
        for (int mb = 0; mb < 4; ++mb)
#pragma unroll
          for (int nbi = 0; nbi < 4; ++nbi)
            acc[mb][nbi] = __builtin_amdgcn_mfma_f32_16x16x32_bf16(
                av[mb], bv[nbi], acc[mb][nbi], 0, 0, 0);
        if (step < 1943) writeB((step + 1) & 1);
        if (t == 80 && step < 1943) {
          __syncthreads();
          int ns = step + 1;
          int npass = ns / 648;
          int ng = (ns % 648) / 81;
          stageA(ng, (npass == 1) ? 1 : 0);
        }
      }
    }
  }

#pragma unroll
  for (int mb = 0; mb < 4; ++mb) {
    int pixb = p0 + (wm * 4 + mb) * 16 + kb * 4;
    if (pixb < 784) {
#pragma unroll
      for (int nbi = 0; nbi < 4; ++nbi) {
        int co = wn * 64 + nbi * 16 + il;
        float bv_ = bias[co];
        f32x4 a = acc[mb][nbi];
        float4 o = make_float4(a[0] + bv_, a[1] + bv_, a[2] + bv_, a[3] + bv_);
        *(float4*)(praw + (size_t)(b * 256 + co) * 784 + pixb) = o;
      }
    }
  }
}

// ---------------------------------------------------------------- capsule squash: p(B,256,784) -> u(B,25088,8)
__global__ __launch_bounds__(256) void squash_caps_k(const float* __restrict__ p,
                                                     float* __restrict__ u) {
  int idx = blockIdx.x * 256 + threadIdx.x;
  if (idx >= BSZ * 25088) return;
  int b = idx / 25088;
  int cap = idx - b * 25088;
  int prim = cap / 784, pix = cap - prim * 784;
  const float* pp = p + ((size_t)b * 256 + prim * 8) * 784 + pix;
  float x[8];
  float sn = 0.f;
#pragma unroll
  for (int d = 0; d < 8; ++d) {
    x[d] = pp[(size_t)d * 784];
    sn += x[d] * x[d];
  }
  float scale = sn / ((1.f + sn) * sqrtf(sn + 1e-8f));
  float4 r0 = {x[0] * scale, x[1] * scale, x[2] * scale, x[3] * scale};
  float4 r1 = {x[4] * scale, x[5] * scale, x[6] * scale, x[7] * scale};
  float4* dst = (float4*)(u + (size_t)idx * 8);
  dst[0] = r0;
  dst[1] = r1;
}

// ---------------------------------------------------------------- u_hat = einsum('iodk,bik->biod')
__global__ __launch_bounds__(256) void uhat_k(const float* __restrict__ u,
                                              const float* __restrict__ w_r,
                                              float* __restrict__ u_hat) {
  int i = blockIdx.x * 256 + threadIdx.x;  // 25088
  int b = blockIdx.y;
  const float4* up = (const float4*)(u + ((size_t)b * 25088 + i) * 8);
  float4 ua = up[0], ub = up[1];
  const float4* wr = (const float4*)(w_r + (size_t)i * 256);
  float res[32];
#pragma unroll
  for (int od = 0; od < 32; ++od) {
    float4 wa = wr[od * 2], wb = wr[od * 2 + 1];
    res[od] = wa.x * ua.x + wa.y * ua.y + wa.z * ua.z + wa.w * ua.w +
              wb.x * ub.x + wb.y * ub.y + wb.z * ub.z + wb.w * ub.w;
  }
  float4* dst = (float4*)(u_hat + ((size_t)b * 25088 + i) * 32);
#pragma unroll
  for (int q = 0; q < 8; ++q)
    dst[q] = make_float4(res[4 * q], res[4 * q + 1], res[4 * q + 2], res[4 * q + 3]);
}

// ---------------------------------------------------------------- routing: partial s_j per (b,seg)
__global__ __launch_bounds__(256) void route_sj_k(const float* __restrict__ u_hat,
                                                  const float* __restrict__ b_ij,
                                                  float* __restrict__ sj_part, int iter) {
  int b = blockIdx.x;
  int seg = blockIdx.y;
  int t = threadIdx.x;
  float acc[32];
#pragma unroll
  for (int j = 0; j < 32; ++j) acc[j] = 0.f;
  int i0 = seg * 3136;
  for (int i = i0 + t; i < i0 + 3136; i += 256) {
    float c0 = 0.5f, c1 = 0.5f;
    if (iter > 0) {
      float b0 = b_ij[((size_t)b * 25088 + i) * 2 + 0];
      float b1 = b_ij[((size_t)b * 25088 + i) * 2 + 1];
      float m = fmaxf(b0, b1);
      float e0 = expf(b0 - m), e1 = expf(b1 - m);
      float inv = 1.f / (e0 + e1);
      c0 = e0 * inv;
      c1 = e1 * inv;
    }
    const float4* uh = (const float4*)(u_hat + ((size_t)b * 25088 + i) * 32);
#pragma unroll
    for (int q = 0; q < 4; ++q) {
      float4 va = uh[q];
      acc[4 * q + 0] += c0 * va.x;
      acc[4 * q + 1] += c0 * va.y;
      acc[4 * q + 2] += c0 * va.z;
      acc[4 * q + 3] += c0 * va.w;
      float4 vb = uh[4 + q];
      acc[16 + 4 * q + 0] += c1 * vb.x;
      acc[16 + 4 * q + 1] += c1 * vb.y;
      acc[16 + 4 * q + 2] += c1 * vb.z;
      acc[16 + 4 * q + 3] += c1 * vb.w;
    }
  }
#pragma unroll
  for (int j = 0; j < 32; ++j) {
    acc[j] += __shfl_down(acc[j], 32);
    acc[j] += __shfl_down(acc[j], 16);
    acc[j] += __shfl_down(acc[j], 8);
    acc[j] += __shfl_down(acc[j], 4);
    acc[j] += __shfl_down(acc[j], 2);
    acc[j] += __shfl_down(acc[j], 1);
  }
  __shared__ float red[4][32];
  int wave = t >> 6, lane = t & 63;
  if (lane == 0) {
#pragma unroll
    for (int j = 0; j < 32; ++j) red[wave][j] = acc[j];
  }
  __syncthreads();
  if (t < 32) {
    float s = red[0][t] + red[1][t] + red[2][t] + red[3][t];
    sj_part[((size_t)b * 8 + seg) * 32 + t] = s;
  }
}

// ---------------------------------------------------------------- routing: finalize v
__global__ __launch_bounds__(256) void route_fin_k(const float* __restrict__ sj_part,
                                                   float* __restrict__ v,
                                                   float* __restrict__ out, int final_it) {
  int idx = blockIdx.x * 256 + threadIdx.x;
  if (idx >= BSZ * 32) return;
  int b = idx >> 5, j = idx & 31;
  float s = 0.f;
#pragma unroll
  for (int seg = 0; seg < 8; ++seg) s += sj_part[((size_t)b * 8 + seg) * 32 + j];
  float sn = s * s;
  float vv = sn * s / ((1.f + sn) * sqrtf(sn + 1e-8f));
  v[idx] = vv;
  if (final_it) out[idx] = fabsf(vv);
}

// ---------------------------------------------------------------- routing: b_ij update
__global__ __launch_bounds__(256) void route_upd_k(const float* __restrict__ u_hat,
                                                   const float* __restrict__ v,
                                                   float* __restrict__ b_ij, int first) {
  int i = blockIdx.x * 256 + threadIdx.x;  // 25088
  int b = blockIdx.y;
  const float4* uh = (const float4*)(u_hat + ((size_t)b * 25088 + i) * 32);
  const float4* vp = (const float4*)(v + b * 32);
  float e0 = 0.f, e1 = 0.f;
#pragma unroll
  for (int q = 0; q < 4; ++q) {
    float4 a = uh[q], wv = vp[q];
    e0 += a.x * wv.x + a.y * wv.y + a.z * wv.z + a.w * wv.w;
    float4 a2 = uh[4 + q], w2 = vp[4 + q];
    e1 += a2.x * w2.x + a2.y * w2.y + a2.z * w2.z + a2.w * w2.w;
  }
  size_t o = ((size_t)b * 25088 + i) * 2;
  if (first) {
    b_ij[o + 0] = e0;
    b_ij[o + 1] = e1;
  } else {
    b_ij[o + 0] += e0;
    b_ij[o + 1] += e1;
  }
}

// ================================================================ launch
extern "C" void kernel_launch(void* const* d_in, const int* in_sizes, int n_in,
                              void* d_out, int out_size, void* d_ws, size_t ws_size,
                              hipStream_t stream) {
  (void)in_sizes; (void)n_in; (void)out_size;
  const float* x    = (const float*)d_in[0];
  const float* w_t1 = (const float*)d_in[1];
  const float* b_t1 = (const float*)d_in[2];
  const float* w_t2 = (const float*)d_in[3];
  const float* b_t2 = (const float*)d_in[4];
  const float* w_t3 = (const float*)d_in[5];
  const float* b_t3 = (const float*)d_in[6];
  const float* w_s1 = (const float*)d_in[7];
  const float* b_s1 = (const float*)d_in[8];
  const float* w_s2 = (const float*)d_in[9];
  const float* b_s2 = (const float*)d_in[10];
  const float* w_s3 = (const float*)d_in[11];
  const float* b_s3 = (const float*)d_in[12];
  const float* w_f  = (const float*)d_in[13];
  const float* b_f  = (const float*)d_in[14];
  const float* w_p  = (const float*)d_in[15];
  const float* b_p  = (const float*)d_in[16];
  const float* w_r  = (const float*)d_in[17];
  float* out = (float*)d_out;

  char* ws = (char*)d_ws;
  if (ws_size < 238854144ull) return;
  // region 0: fused / uhat
  float* fused = (float*)(ws + 0);
  float* uhat  = (float*)(ws + 0);
  // region 1 (134,217,728): s2q -> praw/u/b_ij
  float* s2q   = (float*)(ws + 134217728);
  float* praw  = (float*)(ws + 134217728);
  float* u     = (float*)(ws + 159907840);
  float* b_ij  = (float*)(ws + 185597952);
  // region 2 (201,326,592): s1 -> t1/t2/t3/wTh/wTl
  float* s1    = (float*)(ws + 201326592);
  float* t1    = (float*)(ws + 201326592);
  float* t2    = (float*)(ws + 201850880);
  float* t3    = (float*)(ws + 202899456);
  u16*   wTh   = (u16*)  (ws + 204996608);
  u16*   wTl   = (u16*)  (ws + 215613440);
  // tail (234,881,024): persistent small tables
  u16*   w3a_h = (u16*)  (ws + 234881024);
  u16*   w3a_l = (u16*)  (ws + 235028480);
  u16*   w3b_h = (u16*)  (ws + 235175936);
  u16*   w3b_l = (u16*)  (ws + 235765760);
  float* wfT   = (float*)(ws + 236355584);
  float* sjp   = (float*)(ws + 236621824);
  float* vbuf  = (float*)(ws + 236654592);

  // small weight tables (tail region -- never clobbered)
  transpose_w3_k<128, 2><<<18, 256, 0, stream>>>(w_s2, w3a_h, w3a_l);
  transpose_w3_k<256, 4><<<36, 256, 0, stream>>>(w_s3, w3b_h, w3b_l);
  transpose_wf_k<<<261, 256, 0, stream>>>(w_f, wfT);

  // spectral: s1 scalar conv, then s2 MFMA conv (consumes s1)
  conv3x3_relu_k<1, 1><<<dim3(16, 4, BSZ), 256, 0, stream>>>(x, w_s1, b_s1, s1, 64);
  conv3x3_mfma_k<4, 2, 2, 128><<<dim3(16, BSZ), 512, 0, stream>>>(s1, w3a_h, w3a_l, b_s2, s2q);

  // s1 now dead: temporal branch + 9x9 weight tables move into its region
  conv1d_relu_k<<<512, 256, 0, stream>>>(x, w_t1, b_t1, t1, 64, 64);
  conv1d_relu_k<<<1024, 256, 0, stream>>>(t1, w_t2, b_t2, t2, 64, 128);
  conv1d_relu_k<<<2048, 256, 0, stream>>>(t2, w_t3, b_t3, t3, 128, 256);
  transpose_wp_k<<<648, 256, 0, stream>>>(w_p, wTh, wTl);

  // s3 MFMA conv -> fused
  conv3x3_mfma_k<2, 4, 4, 256><<<dim3(32, BSZ), 512, 0, stream>>>(s2q, w3b_h, w3b_l, b_s3, fused);

  // fusion fp32 in-place
  fuse1x1_k<<<4096, 256, 0, stream>>>(t3, wfT, b_f, fused);

  // primary capsules via MFMA hi/lo (praw over dead s2q)
  conv9x9_mfma_k<<<dim3(7, BSZ), 512, 0, stream>>>(fused, wTh, wTl, b_p, praw);
  squash_caps_k<<<3136, 256, 0, stream>>>(praw, u);

  // u_hat (overwrites fused region)
  uhat_k<<<dim3(98, BSZ), 256, 0, stream>>>(u, w_r, uhat);

  // dynamic routing, 3 iterations
  route_sj_k<<<dim3(BSZ, 8), 256, 0, stream>>>(uhat, b_ij, sjp, 0);
  route_fin_k<<<4, 256, 0, stream>>>(sjp, vbuf, out, 0);
  route_upd_k<<<dim3(98, BSZ), 256, 0, stream>>>(uhat, vbuf, b_ij, 1);

  route_sj_k<<<dim3(BSZ, 8), 256, 0, stream>>>(uhat, b_ij, sjp, 1);
  route_fin_k<<<4, 256, 0, stream>>>(sjp, vbuf, out, 0);
  route_upd_k<<<dim3(98, BSZ), 256, 0, stream>>>(uhat, vbuf, b_ij, 0);

  route_sj_k<<<dim3(BSZ, 8), 256, 0, stream>>>(uhat, b_ij, sjp, 2);
  route_fin_k<<<4, 256, 0, stream>>>(sjp, vbuf, out, 1);
}